// Round 1
// baseline (426.876 us; speedup 1.0000x reference)
//
#include <hip/hip_runtime.h>
#include <stdint.h>

#define SEQ   2048
#define BATCH 4
#define NH    16
#define HD    64
#define DIMN  1024
#define MROWS (BATCH*SEQ)   // 8192

typedef __attribute__((ext_vector_type(8))) short          bf16x8;
typedef __attribute__((ext_vector_type(8))) unsigned short ushort8;
typedef __attribute__((ext_vector_type(4))) float          f32x4;

static __device__ __forceinline__ unsigned short f2bf(float f) {
    unsigned int u = __builtin_bit_cast(unsigned int, f);
    u += 0x7fffu + ((u >> 16) & 1u);          // RNE
    return (unsigned short)(u >> 16);
}

// ---------------------------------------------------------------- cast fp32 -> bf16
__global__ __launch_bounds__(256) void cast_bf16_kernel(const float* __restrict__ src,
                                                        unsigned short* __restrict__ dst, int n) {
    int i = (blockIdx.x * 256 + threadIdx.x) * 8;
    if (i >= n) return;
    float4 a = *(const float4*)(src + i);
    float4 b = *(const float4*)(src + i + 4);
    ushort8 o;
    o[0]=f2bf(a.x); o[1]=f2bf(a.y); o[2]=f2bf(a.z); o[3]=f2bf(a.w);
    o[4]=f2bf(b.x); o[5]=f2bf(b.y); o[6]=f2bf(b.z); o[7]=f2bf(b.w);
    *(ushort8*)(dst + i) = o;
}

// ---------------------------------------------------------------- RoPE tables (fp32, matches ref)
__global__ __launch_bounds__(256) void rope_tables_kernel(float* __restrict__ cosT,
                                                          float* __restrict__ sinT) {
    int idx = blockIdx.x * 256 + threadIdx.x;     // SEQ*32
    int s = idx >> 5, j = idx & 31;
    float t = (float)(2 * j) / 64.0f;
    float freq = 1.0f / powf(10000.0f, t);
    float ang  = (float)s * freq;
    cosT[idx] = cosf(ang);
    sinT[idx] = sinf(ang);
}

// ---------------------------------------------------------------- GEMM  C[m,e] = sum_d A[m,d]*W[e,d] + bias[e]
// MODE 0: write bf16 to [B,H,S,D] (V)
// MODE 1: write bf16 to [B,H,S,D] with RoPE (Q,K)
// MODE 2: write fp32 row-major [M,N] (final projection)
template<int MODE>
__global__ __launch_bounds__(256) void gemm_bt(const unsigned short* __restrict__ A,
                                               const unsigned short* __restrict__ W,
                                               const float* __restrict__ bias,
                                               void* __restrict__ out,
                                               const float* __restrict__ cosT,
                                               const float* __restrict__ sinT) {
    __shared__ __align__(16) unsigned short As[128 * 32];
    __shared__ __align__(16) unsigned short Bs[128 * 32];
    const int tid  = threadIdx.x;
    const int wid  = tid >> 6, lane = tid & 63;
    const int quad = lane >> 4, l15 = lane & 15;
    const int wm   = wid >> 1,  wn  = wid & 1;
    const int m0   = blockIdx.y * 128, n0 = blockIdx.x * 128;

    f32x4 acc[4][4];
#pragma unroll
    for (int i = 0; i < 4; i++)
#pragma unroll
        for (int j = 0; j < 4; j++) acc[i][j] = (f32x4)0.0f;

    const int rb   = wid * 32 + (lane >> 2);   // staging row (per 16-row group add 16*i)
    const int cb   = (lane & 3) * 8;           // staging col (elements)

    for (int k0 = 0; k0 < DIMN; k0 += 32) {
#pragma unroll
        for (int i = 0; i < 2; i++) {
            const unsigned short* ga = A + (size_t)(m0 + rb + i * 16) * DIMN + k0 + cb;
            __builtin_amdgcn_global_load_lds((const __attribute__((address_space(1))) void*)ga,
                (__attribute__((address_space(3))) void*)&As[(wid * 32 + i * 16) * 32], 16, 0, 0);
            const unsigned short* gb = W + (size_t)(n0 + rb + i * 16) * DIMN + k0 + cb;
            __builtin_amdgcn_global_load_lds((const __attribute__((address_space(1))) void*)gb,
                (__attribute__((address_space(3))) void*)&Bs[(wid * 32 + i * 16) * 32], 16, 0, 0);
        }
        __syncthreads();
        bf16x8 af[4], bfr[4];
#pragma unroll
        for (int f = 0; f < 4; f++) af[f]  = *(const bf16x8*)&As[(wm * 64 + f * 16 + l15) * 32 + quad * 8];
#pragma unroll
        for (int f = 0; f < 4; f++) bfr[f] = *(const bf16x8*)&Bs[(wn * 64 + f * 16 + l15) * 32 + quad * 8];
#pragma unroll
        for (int fm = 0; fm < 4; fm++)
#pragma unroll
            for (int fn = 0; fn < 4; fn++)
                acc[fm][fn] = __builtin_amdgcn_mfma_f32_16x16x32_bf16(af[fm], bfr[fn], acc[fm][fn], 0, 0, 0);
        __syncthreads();
    }

    float bv[4];
#pragma unroll
    for (int fn = 0; fn < 4; fn++) bv[fn] = bias[n0 + wn * 64 + fn * 16 + l15];

    if (MODE == 2) {
        float* O = (float*)out;
#pragma unroll
        for (int fm = 0; fm < 4; fm++)
#pragma unroll
            for (int r = 0; r < 4; r++) {
                int mrow = m0 + wm * 64 + fm * 16 + quad * 4 + r;
                float* orow = O + (size_t)mrow * DIMN + n0 + wn * 64;
#pragma unroll
                for (int fn = 0; fn < 4; fn++) orow[fn * 16 + l15] = acc[fm][fn][r] + bv[fn];
            }
    } else {
        unsigned short* Ob = (unsigned short*)out;
        const int h = blockIdx.x * 2 + wn;     // wave's 64 cols = one head
#pragma unroll
        for (int fm = 0; fm < 4; fm++)
#pragma unroll
            for (int r = 0; r < 4; r++) {
                int mrow = m0 + wm * 64 + fm * 16 + quad * 4 + r;
                int b = mrow >> 11, s = mrow & (SEQ - 1);
                unsigned short* orow = Ob + ((size_t)(b * NH + h) * SEQ + s) * HD;
                float v0 = acc[fm][0][r] + bv[0];
                float v1 = acc[fm][1][r] + bv[1];
                float v2 = acc[fm][2][r] + bv[2];
                float v3 = acc[fm][3][r] + bv[3];
                if (MODE == 1) {
                    int d0 = l15, d1 = 16 + l15;
                    float c0 = cosT[s * 32 + d0], n0r = sinT[s * 32 + d0];
                    float c1 = cosT[s * 32 + d1], n1r = sinT[s * 32 + d1];
                    orow[d0]      = f2bf(v0 * c0 - v2 * n0r);
                    orow[d0 + 32] = f2bf(v0 * n0r + v2 * c0);
                    orow[d1]      = f2bf(v1 * c1 - v3 * n1r);
                    orow[d1 + 32] = f2bf(v1 * n1r + v3 * c1);
                } else {
                    orow[l15]      = f2bf(v0);
                    orow[16 + l15] = f2bf(v1);
                    orow[32 + l15] = f2bf(v2);
                    orow[48 + l15] = f2bf(v3);
                }
            }
    }
}

// ---------------------------------------------------------------- flash attention
// grid: (SEQ/64, BATCH*NH). 4 waves x 16 q-rows. Computes S^T = K*Q^T so the
// softmax row (q) is lane&15 (2 shuffles) and P^T scatters conflict-free into
// A-operand layout Ps[q][kk]. V transposed into LDS at staging (Vt[d][kk]).
__global__ __launch_bounds__(256) void attn_kernel(const unsigned short* __restrict__ Q,
                                                   const unsigned short* __restrict__ K,
                                                   const unsigned short* __restrict__ V,
                                                   const unsigned char* __restrict__ mask,
                                                   unsigned short* __restrict__ Ob) {
    __shared__ __align__(16) unsigned short Ks[64 * 72];
    __shared__ __align__(16) unsigned short Vt[64 * 72];
    __shared__ __align__(16) unsigned short Ps[4][16 * 72];
    const int tid  = threadIdx.x;
    const int wid  = tid >> 6, lane = tid & 63;
    const int quad = lane >> 4, l15 = lane & 15;
    const int bh = blockIdx.y, b = bh >> 4, h = bh & 15;
    const int q0 = blockIdx.x * 64;

    // Q fragments (B-operand layout: n=q=l15, k=d)
    const int qs = q0 + wid * 16 + l15;
    bf16x8 qf[2];
#pragma unroll
    for (int ks = 0; ks < 2; ks++)
        qf[ks] = __builtin_bit_cast(bf16x8,
            *(const uint4*)&Q[((size_t)bh * SEQ + qs) * HD + ks * 32 + quad * 8]);

    f32x4 Oa[4];
#pragma unroll
    for (int i = 0; i < 4; i++) Oa[i] = (f32x4)0.0f;
    float m_run = -1e30f, l_run = 0.0f;

    for (int kt = 0; kt < SEQ / 64; kt++) {
        const int k0 = kt * 64;
        // stage K (row-major, stride 72) and V (transposed: Vt[d][kk])
#pragma unroll
        for (int i = 0; i < 2; i++) {
            int d0 = (wid + 4 * i) * 8;
            size_t g = ((size_t)bh * SEQ + k0 + lane) * HD + d0;
            uint4 kv = *(const uint4*)&K[g];
            *(uint4*)&Ks[lane * 72 + d0] = kv;
            ushort8 vv = __builtin_bit_cast(ushort8, *(const uint4*)&V[g]);
#pragma unroll
            for (int j = 0; j < 8; j++) Vt[(d0 + j) * 72 + lane] = vv[j];
        }
        unsigned char mvb = mask[b * SEQ + k0 + lane];
        unsigned long long mb = __ballot(mvb != 0);
        __syncthreads();

        // S^T = K * Q^T : m=kk (4 frags), n=q (wave's 16 rows)
        f32x4 st[4];
#pragma unroll
        for (int f = 0; f < 4; f++) st[f] = (f32x4)0.0f;
#pragma unroll
        for (int f = 0; f < 4; f++)
#pragma unroll
            for (int ks = 0; ks < 2; ks++) {
                bf16x8 kf = *(const bf16x8*)&Ks[(f * 16 + l15) * 72 + ks * 32 + quad * 8];
                st[f] = __builtin_amdgcn_mfma_f32_16x16x32_bf16(kf, qf[ks], st[f], 0, 0, 0);
            }

        // scale + mask + online softmax (q = l15 per lane)
        float mx = -1e30f;
#pragma unroll
        for (int f = 0; f < 4; f++)
#pragma unroll
            for (int r = 0; r < 4; r++) {
                int kk = f * 16 + quad * 4 + r;
                float v = st[f][r] * 0.125f;
                if ((mb >> kk) & 1ull) v = -1e9f;
                st[f][r] = v;
                mx = fmaxf(mx, v);
            }
        mx = fmaxf(mx, __shfl_xor(mx, 16));
        mx = fmaxf(mx, __shfl_xor(mx, 32));
        float m_new = fmaxf(m_run, mx);
        float alpha = __expf(m_run - m_new);
        float rs = 0.0f;
#pragma unroll
        for (int f = 0; f < 4; f++)
#pragma unroll
            for (int r = 0; r < 4; r++) {
                int kk = f * 16 + quad * 4 + r;
                float p = __expf(st[f][r] - m_new);
                rs += p;
                Ps[wid][l15 * 72 + kk] = f2bf(p);
            }
        rs += __shfl_xor(rs, 16);
        rs += __shfl_xor(rs, 32);
        l_run = l_run * alpha + rs;
        m_run = m_new;

        float a4[4];
#pragma unroll
        for (int r = 0; r < 4; r++) a4[r] = __shfl(alpha, quad * 4 + r);
#pragma unroll
        for (int nf = 0; nf < 4; nf++)
#pragma unroll
            for (int r = 0; r < 4; r++) Oa[nf][r] *= a4[r];

        __syncthreads();   // conservative: ensure Ps visible (also keeps waves in step)

        // PV: A = P (Ps[q][kk]), B = V (Vt[d][kk] -> B[kk][d])
#pragma unroll
        for (int ks = 0; ks < 2; ks++) {
            bf16x8 pf = *(const bf16x8*)&Ps[wid][l15 * 72 + ks * 32 + quad * 8];
#pragma unroll
            for (int nf = 0; nf < 4; nf++) {
                bf16x8 vf = *(const bf16x8*)&Vt[(nf * 16 + l15) * 72 + ks * 32 + quad * 8];
                Oa[nf] = __builtin_amdgcn_mfma_f32_16x16x32_bf16(pf, vf, Oa[nf], 0, 0, 0);
            }
        }
        __syncthreads();
    }

    float li[4];
#pragma unroll
    for (int r = 0; r < 4; r++) li[r] = 1.0f / __shfl(l_run, quad * 4 + r);
#pragma unroll
    for (int r = 0; r < 4; r++) {
        int srow = q0 + wid * 16 + quad * 4 + r;
        unsigned short* orow = Ob + ((size_t)b * SEQ + srow) * DIMN + h * HD;
#pragma unroll
        for (int nf = 0; nf < 4; nf++) orow[nf * 16 + l15] = f2bf(Oa[nf][r] * li[r]);
    }
}

// ---------------------------------------------------------------- launch
extern "C" void kernel_launch(void* const* d_in, const int* in_sizes, int n_in,
                              void* d_out, int out_size, void* d_ws, size_t ws_size,
                              hipStream_t stream) {
    (void)in_sizes; (void)n_in; (void)out_size; (void)ws_size;
    const float* x  = (const float*)d_in[0];
    const unsigned char* mask = (const unsigned char*)d_in[1];
    const float* q_w = (const float*)d_in[2];
    const float* q_b = (const float*)d_in[3];
    const float* k_w = (const float*)d_in[4];
    const float* k_b = (const float*)d_in[5];
    const float* v_w = (const float*)d_in[6];
    const float* v_b = (const float*)d_in[7];
    const float* o_w = (const float*)d_in[8];
    const float* o_b = (const float*)d_in[9];
    float* out = (float*)d_out;

    char* w = (char*)d_ws;
    unsigned short* xb = (unsigned short*)w;                        // 16 MiB (reused as attn output)
    unsigned short* wq = (unsigned short*)(w + (16u << 20));        // 4 x 2 MiB
    unsigned short* wk = wq + (1u << 20);
    unsigned short* wv = wk + (1u << 20);
    unsigned short* wo = wv + (1u << 20);
    float* cosT = (float*)(w + (24u << 20));                        // 256 KiB
    float* sinT = cosT + SEQ * 32;                                  // 256 KiB
    unsigned short* Qb = (unsigned short*)(w + (25u << 20));        // 3 x 16 MiB
    unsigned short* Kb = Qb + (8u << 20);
    unsigned short* Vb = Kb + (8u << 20);
    unsigned short* Ob = xb;                                        // reuse x's slot

    cast_bf16_kernel<<<dim3(MROWS * DIMN / 2048), 256, 0, stream>>>(x,   xb, MROWS * DIMN);
    cast_bf16_kernel<<<dim3(DIMN * DIMN / 2048), 256, 0, stream>>>(q_w, wq, DIMN * DIMN);
    cast_bf16_kernel<<<dim3(DIMN * DIMN / 2048), 256, 0, stream>>>(k_w, wk, DIMN * DIMN);
    cast_bf16_kernel<<<dim3(DIMN * DIMN / 2048), 256, 0, stream>>>(v_w, wv, DIMN * DIMN);
    cast_bf16_kernel<<<dim3(DIMN * DIMN / 2048), 256, 0, stream>>>(o_w, wo, DIMN * DIMN);
    rope_tables_kernel<<<dim3(SEQ * 32 / 256), 256, 0, stream>>>(cosT, sinT);

    gemm_bt<1><<<dim3(DIMN / 128, MROWS / 128), 256, 0, stream>>>(xb, wq, q_b, Qb, cosT, sinT);
    gemm_bt<1><<<dim3(DIMN / 128, MROWS / 128), 256, 0, stream>>>(xb, wk, k_b, Kb, cosT, sinT);
    gemm_bt<0><<<dim3(DIMN / 128, MROWS / 128), 256, 0, stream>>>(xb, wv, v_b, Vb, nullptr, nullptr);

    attn_kernel<<<dim3(SEQ / 64, BATCH * NH), 256, 0, stream>>>(Qb, Kb, Vb, mask, Ob);

    gemm_bt<2><<<dim3(DIMN / 128, MROWS / 128), 256, 0, stream>>>(Ob, wo, o_b, out, nullptr, nullptr);
}